// Round 1
// baseline (156.927 us; speedup 1.0000x reference)
//
#include <hip/hip_runtime.h>

// Problem constants
#define B_     256
#define NOBJ   32
#define DIM    128
#define HW     256          // MSG_W == FIN_W == 256
#define R1     8192         // B*NOBJ rows
#define NPAIR  262144       // B*NOBJ*NOBJ rows
#define BN_EPS 1e-5f

// ---------------------------------------------------------------------------
// Generic small GEMM: C[m, coff+n] = sum_k A[m,k]*W[n,k] + bias_scale*bias[n]
// Tiles 64x64, BK=32, 256 threads, each thread 4x4 micro-tile.
// Grid: (N/64, M/64). Requires M%64==0, N%64==0, K%32==0.
// ---------------------------------------------------------------------------
__global__ __launch_bounds__(256) void gemm_bias(
    const float* __restrict__ A, int lda,
    const float* __restrict__ W, int ldw,
    const float* __restrict__ bias, float bias_scale,
    float* __restrict__ C, int ldc, int coff,
    int K)
{
    __shared__ float As[32][64];
    __shared__ float Ws[32][64];

    const int t   = threadIdx.x;
    const int tx  = t & 15;
    const int ty  = t >> 4;
    const int row0 = blockIdx.y * 64;
    const int col0 = blockIdx.x * 64;
    const int lm  = t >> 2;          // 0..63
    const int lk  = (t & 3) << 2;    // 0,4,8,12

    float acc[4][4] = {{0.f,0.f,0.f,0.f},{0.f,0.f,0.f,0.f},
                       {0.f,0.f,0.f,0.f},{0.f,0.f,0.f,0.f}};

    for (int k0 = 0; k0 < K; k0 += 32) {
        float4 a0 = *(const float4*)(A + (size_t)(row0 + lm) * lda + k0 + lk);
        float4 a1 = *(const float4*)(A + (size_t)(row0 + lm) * lda + k0 + lk + 16);
        float4 w0 = *(const float4*)(W + (size_t)(col0 + lm) * ldw + k0 + lk);
        float4 w1 = *(const float4*)(W + (size_t)(col0 + lm) * ldw + k0 + lk + 16);
        __syncthreads();   // previous iteration's compute done before overwrite
        As[lk + 0][lm] = a0.x; As[lk + 1][lm] = a0.y;
        As[lk + 2][lm] = a0.z; As[lk + 3][lm] = a0.w;
        As[lk + 16][lm] = a1.x; As[lk + 17][lm] = a1.y;
        As[lk + 18][lm] = a1.z; As[lk + 19][lm] = a1.w;
        Ws[lk + 0][lm] = w0.x; Ws[lk + 1][lm] = w0.y;
        Ws[lk + 2][lm] = w0.z; Ws[lk + 3][lm] = w0.w;
        Ws[lk + 16][lm] = w1.x; Ws[lk + 17][lm] = w1.y;
        Ws[lk + 18][lm] = w1.z; Ws[lk + 19][lm] = w1.w;
        __syncthreads();
        #pragma unroll
        for (int kk = 0; kk < 32; ++kk) {
            float av[4], wv[4];
            #pragma unroll
            for (int i = 0; i < 4; ++i) av[i] = As[kk][ty * 4 + i];
            #pragma unroll
            for (int j = 0; j < 4; ++j) wv[j] = Ws[kk][tx * 4 + j];
            #pragma unroll
            for (int i = 0; i < 4; ++i)
                #pragma unroll
                for (int j = 0; j < 4; ++j)
                    acc[i][j] = fmaf(av[i], wv[j], acc[i][j]);
        }
    }

    #pragma unroll
    for (int i = 0; i < 4; ++i) {
        const int r = row0 + ty * 4 + i;
        float* Crow = C + (size_t)r * ldc + coff + col0;
        #pragma unroll
        for (int j = 0; j < 4; ++j) {
            float v = acc[i][j];
            if (bias) v = fmaf(bias_scale, bias[col0 + tx * 4 + j], v);
            Crow[tx * 4 + j] = v;
        }
    }
}

// ---------------------------------------------------------------------------
// Stats over implicit H1 = e*(P+Q)+b1 : one block per batch, thread = column.
// ---------------------------------------------------------------------------
__global__ __launch_bounds__(256) void stats1_kernel(
    const float* __restrict__ P, const float* __restrict__ Q,
    const float* __restrict__ edges, const float* __restrict__ b1,
    float* __restrict__ sums)
{
    __shared__ float Qs[NOBJ * HW];   // 32 KB
    __shared__ float es[NOBJ * NOBJ]; // 4 KB
    const int b = blockIdx.x;
    const int t = threadIdx.x;

    const float* Qb = Q + (size_t)b * (NOBJ * HW);
    for (int idx = t; idx < NOBJ * HW; idx += 256) Qs[idx] = Qb[idx];
    for (int idx = t; idx < NOBJ * NOBJ; idx += 256) es[idx] = edges[(size_t)b * (NOBJ * NOBJ) + idx];
    __syncthreads();

    const float bk = b1[t];
    const float* Pb = P + (size_t)b * (NOBJ * HW);
    float s = 0.f, ss = 0.f;
    for (int i = 0; i < NOBJ; ++i) {
        const float p = Pb[i * HW + t];
        const float* er = es + i * NOBJ;
        #pragma unroll
        for (int j = 0; j < NOBJ; ++j) {
            const float x = fmaf(er[j], p + Qs[j * HW + t], bk);
            s += x;
            ss = fmaf(x, x, ss);
        }
    }
    atomicAdd(&sums[t], s);
    atomicAdd(&sums[HW + t], ss);
}

__global__ void finalize1_kernel(const float* __restrict__ sums,
                                 const float* __restrict__ gamma,
                                 const float* __restrict__ beta,
                                 const float* __restrict__ b1,
                                 float* __restrict__ ad, float invN)
{
    const int t = threadIdx.x;
    const float mean = sums[t] * invN;
    const float var  = fmaf(-mean, mean, sums[HW + t] * invN);
    const float inv  = rsqrtf(var + BN_EPS);
    const float a    = gamma[t] * inv;
    ad[t]      = a;
    ad[HW + t] = fmaf(b1[t] - mean, a, beta[t]);  // (b1-mean)*a + beta
}

// ---------------------------------------------------------------------------
// S[b,i,k] = sum_j lrelu( e*(P+Q)*a + d )
// ---------------------------------------------------------------------------
__global__ __launch_bounds__(256) void s_kernel(
    const float* __restrict__ P, const float* __restrict__ Q,
    const float* __restrict__ edges, const float* __restrict__ ad,
    float* __restrict__ S)
{
    __shared__ float Qs[NOBJ * HW];
    __shared__ float es[NOBJ * NOBJ];
    const int b = blockIdx.x;
    const int t = threadIdx.x;

    const float* Qb = Q + (size_t)b * (NOBJ * HW);
    for (int idx = t; idx < NOBJ * HW; idx += 256) Qs[idx] = Qb[idx];
    for (int idx = t; idx < NOBJ * NOBJ; idx += 256) es[idx] = edges[(size_t)b * (NOBJ * NOBJ) + idx];
    __syncthreads();

    const float a  = ad[t];
    const float dk = ad[HW + t];
    const float* Pb = P + (size_t)b * (NOBJ * HW);
    for (int i = 0; i < NOBJ; ++i) {
        const float p = Pb[i * HW + t];
        const float* er = es + i * NOBJ;
        float acc = 0.f;
        #pragma unroll
        for (int j = 0; j < NOBJ; ++j) {
            const float x = fmaf(er[j] * (p + Qs[j * HW + t]), a, dk);
            acc += (x >= 0.f) ? x : 0.01f * x;
        }
        S[(size_t)b * (NOBJ * HW) + i * HW + t] = acc;
    }
}

// ---------------------------------------------------------------------------
__global__ void copy_state_kernel(const float4* __restrict__ state, float* __restrict__ SM)
{
    const int idx = blockIdx.x * 256 + threadIdx.x;  // 8192*32 float4
    if (idx < R1 * (DIM / 4)) {
        const int r  = idx >> 5;
        const int c4 = idx & 31;
        *(float4*)(SM + (size_t)r * HW + c4 * 4) = state[idx];
    }
}

__global__ void stats2_kernel(const float* __restrict__ H2, float* __restrict__ sums)
{
    const int t = threadIdx.x;
    const int blk = blockIdx.x;
    float s = 0.f, ss = 0.f;
    for (int r = 0; r < 128; ++r) {
        const float x = H2[(size_t)(blk * 128 + r) * HW + t];
        s += x;
        ss = fmaf(x, x, ss);
    }
    atomicAdd(&sums[t], s);
    atomicAdd(&sums[HW + t], ss);
}

__global__ void finalize2_kernel(const float* __restrict__ sums,
                                 const float* __restrict__ gamma,
                                 const float* __restrict__ beta,
                                 float* __restrict__ ad, float invN)
{
    const int t = threadIdx.x;
    const float mean = sums[t] * invN;
    const float var  = fmaf(-mean, mean, sums[HW + t] * invN);
    const float inv  = rsqrtf(var + BN_EPS);
    const float a    = gamma[t] * inv;
    ad[t]      = a;
    ad[HW + t] = fmaf(-mean, a, beta[t]);   // beta - mean*a  (bias already in H2)
}

__global__ void act2_kernel(float* __restrict__ H2, const float* __restrict__ ad)
{
    const int idx = blockIdx.x * 256 + threadIdx.x;  // 8192*256
    const int k = idx & (HW - 1);
    const float x = fmaf(H2[idx], ad[k], ad[HW + k]);
    H2[idx] = (x >= 0.f) ? x : 0.01f * x;
}

// ---------------------------------------------------------------------------
extern "C" void kernel_launch(void* const* d_in, const int* in_sizes, int n_in,
                              void* d_out, int out_size, void* d_ws, size_t ws_size,
                              hipStream_t stream)
{
    const float* state     = (const float*)d_in[0];
    const float* edges     = (const float*)d_in[1];
    const float* msg_w1    = (const float*)d_in[2];
    const float* msg_b1    = (const float*)d_in[3];
    const float* msg_gamma = (const float*)d_in[4];
    const float* msg_beta  = (const float*)d_in[5];
    const float* msg_w2    = (const float*)d_in[6];
    const float* msg_b2    = (const float*)d_in[7];
    const float* fin_w1    = (const float*)d_in[8];
    const float* fin_b1    = (const float*)d_in[9];
    const float* fin_gamma = (const float*)d_in[10];
    const float* fin_beta  = (const float*)d_in[11];
    const float* fin_w2    = (const float*)d_in[12];
    const float* fin_b2    = (const float*)d_in[13];
    float* out = (float*)d_out;
    float* ws  = (float*)d_ws;

    // workspace layout (floats)
    float* P   = ws;                  // 8192*256
    float* Q   = ws + 2097152;        // 8192*256
    float* S   = ws + 4194304;        // 8192*256
    float* SM  = ws;                  // overlays P (free after s_kernel)
    float* H2  = ws + 2097152;        // overlays Q (free after s_kernel)
    float* st  = ws + 6291456;        // stats region: 2048 floats
    float* sums1 = st;
    float* ad1   = st + 512;
    float* sums2 = st + 1024;
    float* ad2   = st + 1536;

    hipMemsetAsync(st, 0, 2048 * sizeof(float), stream);

    const dim3 blk(256);

    // P = state @ W1a^T ; Q = state @ W1b^T   (no bias)
    gemm_bias<<<dim3(HW / 64, R1 / 64), blk, 0, stream>>>(
        state, DIM, msg_w1, 2 * DIM, nullptr, 0.f, P, HW, 0, DIM);
    gemm_bias<<<dim3(HW / 64, R1 / 64), blk, 0, stream>>>(
        state, DIM, msg_w1 + DIM, 2 * DIM, nullptr, 0.f, Q, HW, 0, DIM);

    stats1_kernel<<<B_, blk, 0, stream>>>(P, Q, edges, msg_b1, sums1);
    finalize1_kernel<<<1, blk, 0, stream>>>(sums1, msg_gamma, msg_beta, msg_b1, ad1,
                                            1.f / (float)NPAIR);
    s_kernel<<<B_, blk, 0, stream>>>(P, Q, edges, ad1, S);

    // SM = [state | agg]
    copy_state_kernel<<<(R1 * (DIM / 4)) / 256, blk, 0, stream>>>((const float4*)state, SM);
    gemm_bias<<<dim3(DIM / 64, R1 / 64), blk, 0, stream>>>(
        S, HW, msg_w2, HW, msg_b2, (float)NOBJ, SM, HW, DIM, HW);

    // H2 = SM @ fin_w1^T + fin_b1
    gemm_bias<<<dim3(HW / 64, R1 / 64), blk, 0, stream>>>(
        SM, HW, fin_w1, 2 * DIM, fin_b1, 1.f, H2, HW, 0, 2 * DIM);

    stats2_kernel<<<64, blk, 0, stream>>>(H2, sums2);
    finalize2_kernel<<<1, blk, 0, stream>>>(sums2, fin_gamma, fin_beta, ad2,
                                            1.f / (float)R1);
    act2_kernel<<<(R1 * HW) / 256, blk, 0, stream>>>(H2, ad2);

    // out = act(H2) @ fin_w2^T + fin_b2
    gemm_bias<<<dim3(DIM / 64, R1 / 64), blk, 0, stream>>>(
        H2, HW, fin_w2, HW, fin_b2, 1.f, out, DIM, 0, HW);
}